// Round 5
// baseline (190.891 us; speedup 1.0000x reference)
//
#include <hip/hip_runtime.h>

#define NQ 16384
#define NV 16384
#define DMODEL 256

typedef __bf16 bf16x8 __attribute__((ext_vector_type(8)));
typedef float f32x4 __attribute__((ext_vector_type(4)));

__device__ __forceinline__ unsigned short f2bf(float x) {
    union { float f; unsigned int u; } v; v.f = x;
    unsigned int r = v.u + 0x7fff + ((v.u >> 16) & 1);
    return (unsigned short)(r >> 16);
}
__device__ __forceinline__ float blo(unsigned int u) {
    union { unsigned int u; float f; } v; v.u = u << 16; return v.f;
}
__device__ __forceinline__ float bhi(unsigned int u) {
    union { unsigned int u; float f; } v; v.u = u & 0xFFFF0000u; return v.f;
}
__device__ __forceinline__ f32x4 mfma16(bf16x8 a, bf16x8 b, f32x4 c) {
    return __builtin_amdgcn_mfma_f32_16x16x32_bf16(a, b, c, 0, 0, 0);
}

// ---------------- prep: transpose weights to bf16 [n][k] ----------------
__global__ __launch_bounds__(256) void k_prep(
    const float* __restrict__ Wv, const float* __restrict__ Woff,
    const float* __restrict__ Wattn, const float* __restrict__ Wout,
    unsigned short* __restrict__ WtV, unsigned short* __restrict__ WtC,
    unsigned short* __restrict__ WtO) {
    int t = blockIdx.x * 256 + threadIdx.x;
    if (t < 256 * 256) { int n = t >> 8, k = t & 255; WtV[t] = f2bf(Wv[k * 256 + n]); return; }
    t -= 256 * 256;
    if (t < 256 * 256) { int n = t >> 8, k = t & 255; WtO[t] = f2bf(Wout[k * 256 + n]); return; }
    t -= 256 * 256;
    if (t < 96 * 256) {
        int j = t >> 8, k = t & 255;
        float w = (j < 64) ? Woff[k * 64 + j] : Wattn[k * 32 + (j - 64)];
        WtC[j * 256 + k] = f2bf(w);
    }
}

// ---------------- streaming LN: feat->lnf, query->lnq (bf16) ----------------
// 16-lane row groups; each wave does 8 rows (two quads, all loads upfront).
// No LDS, high occupancy => latency fully hidden.
__global__ __launch_bounds__(256) void k_ln(
    const float* __restrict__ feat, const float* __restrict__ query,
    const float* __restrict__ fns, const float* __restrict__ fnb,
    const float* __restrict__ qns, const float* __restrict__ qnb,
    unsigned short* __restrict__ lnf, unsigned short* __restrict__ lnq) {
    const int blk = blockIdx.x;
    const float* src; const float* scale; const float* bias; unsigned short* dst;
    int row0;
    if (blk < 2048) { src = feat;  scale = fns; bias = fnb; dst = lnf; row0 = blk * 32; }
    else            { src = query; scale = qns; bias = qnb; dst = lnq; row0 = (blk - 2048) * 32; }
    const int lane = threadIdx.x & 63;
    const int w = threadIdx.x >> 6;
    const int g = lane >> 4, li = lane & 15;
    float4 sc[4], bi[4];
#pragma unroll
    for (int j = 0; j < 4; ++j) {
        sc[j] = *(const float4*)(scale + li * 16 + j * 4);
        bi[j] = *(const float4*)(bias + li * 16 + j * 4);
    }
    const int r0 = row0 + w * 8 + g;
    float4 x[2][4];
#pragma unroll
    for (int h2 = 0; h2 < 2; ++h2)
#pragma unroll
        for (int j = 0; j < 4; ++j)
            x[h2][j] = *(const float4*)(src + (size_t)(r0 + h2 * 4) * 256 + li * 16 + j * 4);
#pragma unroll
    for (int h2 = 0; h2 < 2; ++h2) {
        float s = 0.f, sq = 0.f;
#pragma unroll
        for (int j = 0; j < 4; ++j) {
            s  += x[h2][j].x + x[h2][j].y + x[h2][j].z + x[h2][j].w;
            sq += x[h2][j].x * x[h2][j].x + x[h2][j].y * x[h2][j].y +
                  x[h2][j].z * x[h2][j].z + x[h2][j].w * x[h2][j].w;
        }
#pragma unroll
        for (int d = 1; d < 16; d <<= 1) {
            s  += __shfl_xor(s, d);
            sq += __shfl_xor(sq, d);
        }
        float mu = s * 0.00390625f;
        float rstd = rsqrtf(sq * 0.00390625f - mu * mu + 1e-6f);
        unsigned int pk[8];
#pragma unroll
        for (int j = 0; j < 4; ++j) {
            pk[2 * j] = (unsigned)f2bf((x[h2][j].x - mu) * rstd * sc[j].x + bi[j].x) |
                        ((unsigned)f2bf((x[h2][j].y - mu) * rstd * sc[j].y + bi[j].y) << 16);
            pk[2 * j + 1] = (unsigned)f2bf((x[h2][j].z - mu) * rstd * sc[j].z + bi[j].z) |
                            ((unsigned)f2bf((x[h2][j].w - mu) * rstd * sc[j].w + bi[j].w) << 16);
        }
        uint4* dstp = (uint4*)(dst + (size_t)(r0 + h2 * 4) * 256 + li * 16);
        dstp[0] = make_uint4(pk[0], pk[1], pk[2], pk[3]);
        dstp[1] = make_uint4(pk[4], pk[5], pk[6], pk[7]);
    }
}

#define STAGE_A(srcbuf)                                                               \
    {                                                                                 \
        const int c = threadIdx.x & 31;                                               \
        const int rt = threadIdx.x >> 5;                                              \
        _Pragma("unroll") for (int i = 0; i < 16; ++i) {                              \
            const int r = rt + i * 8;                                                 \
            *(uint4*)&A[r * 264 + c * 8] =                                            \
                *(const uint4*)((srcbuf) + (size_t)(m0 + r) * 256 + c * 8);           \
        }                                                                             \
    }

#define MFMA_STEP_V(bf, kk)                                                           \
    _Pragma("unroll") for (int m = 0; m < 8; ++m) {                                   \
        bf16x8 a = *(const bf16x8*)&A[(m * 16 + lrow) * 264 + (kk) * 32 + lk];        \
        _Pragma("unroll") for (int i = 0; i < 4; ++i)                                 \
            acc[i][m] = mfma16(bf[i], a, acc[i][m]);                                  \
    }

// ---------------- value GEMM: lnf @ WtV^T + b_value -> bf16 value ----------------
__global__ __launch_bounds__(256) void k_value(
    const unsigned short* __restrict__ lnf, const float* __restrict__ b_value,
    const unsigned short* __restrict__ WtV, unsigned short* __restrict__ value) {
    __shared__ unsigned short A[128 * 264];
    const int m0 = blockIdx.x * 128;
    STAGE_A(lnf)
    __syncthreads();
    const int lane = threadIdx.x & 63;
    const int w = threadIdx.x >> 6;
    const int lrow = lane & 15, lk = (lane >> 4) * 8;
    f32x4 acc[4][8];
#pragma unroll
    for (int i = 0; i < 4; ++i)
#pragma unroll
        for (int m = 0; m < 8; ++m) acc[i][m] = (f32x4){0.f, 0.f, 0.f, 0.f};
#define LOADB_V(dst, kk)                                                              \
    _Pragma("unroll") for (int i = 0; i < 4; ++i) dst[i] =                            \
        *(const bf16x8*)(WtV + (size_t)((w * 4 + i) * 16 + lrow) * 256 + (kk) * 32 + lk);
    {
        bf16x8 b0[4], b1[4];
        LOADB_V(b0, 0)
#pragma unroll
        for (int k2 = 0; k2 < 4; ++k2) {
            LOADB_V(b1, k2 * 2 + 1)
            MFMA_STEP_V(b0, k2 * 2)
            if (k2 < 3) { LOADB_V(b0, k2 * 2 + 2) }
            MFMA_STEP_V(b1, k2 * 2 + 1)
        }
    }
    const int g = lane >> 4;
    float4 bv[4];
#pragma unroll
    for (int i = 0; i < 4; ++i) bv[i] = *(const float4*)(b_value + (w * 4 + i) * 16 + g * 4);
#pragma unroll
    for (int m = 0; m < 8; ++m) {
        const size_t row = (size_t)(m0 + m * 16 + (lane & 15));
#pragma unroll
        for (int i = 0; i < 4; ++i) {
            const int col0 = (w * 4 + i) * 16 + g * 4;
            uint2 r;
            r.x = (unsigned)f2bf(acc[i][m][0] + bv[i].x) | ((unsigned)f2bf(acc[i][m][1] + bv[i].y) << 16);
            r.y = (unsigned)f2bf(acc[i][m][2] + bv[i].z) | ((unsigned)f2bf(acc[i][m][3] + bv[i].w) << 16);
            *(uint2*)(value + row * 256 + col0) = r;
        }
    }
}

// ---------------- qoff GEMM + softmax -> samples ----------------
__global__ __launch_bounds__(256) void k_qoff(
    const unsigned short* __restrict__ lnq, const float* __restrict__ refpt,
    const float* __restrict__ b_off, const float* __restrict__ b_attn,
    const unsigned short* __restrict__ WtC, float4* __restrict__ samples) {
    __shared__ unsigned short A[128 * 264];
    const int m0 = blockIdx.x * 128;
    STAGE_A(lnq)
    __syncthreads();
    const int lane = threadIdx.x & 63;
    const int w = threadIdx.x >> 6;
    const int lrow = lane & 15, lk = (lane >> 4) * 8;
    f32x4 acc[6][2];
#pragma unroll
    for (int i = 0; i < 6; ++i)
#pragma unroll
        for (int m = 0; m < 2; ++m) acc[i][m] = (f32x4){0.f, 0.f, 0.f, 0.f};
#define LOADB_Q(dst, kk)                                                              \
    _Pragma("unroll") for (int i = 0; i < 6; ++i) dst[i] =                            \
        *(const bf16x8*)(WtC + (size_t)(i * 16 + lrow) * 256 + (kk) * 32 + lk);
#define MFMA_STEP_Q(bf, kk)                                                           \
    _Pragma("unroll") for (int m = 0; m < 2; ++m) {                                   \
        bf16x8 a = *(const bf16x8*)&A[(w * 32 + m * 16 + lrow) * 264 + (kk) * 32 + lk]; \
        _Pragma("unroll") for (int i = 0; i < 6; ++i)                                 \
            acc[i][m] = mfma16(bf[i], a, acc[i][m]);                                  \
    }
    {
        bf16x8 b0[6], b1[6];
        LOADB_Q(b0, 0)
#pragma unroll
        for (int k2 = 0; k2 < 4; ++k2) {
            LOADB_Q(b1, k2 * 2 + 1)
            MFMA_STEP_Q(b0, k2 * 2)
            if (k2 < 3) { LOADB_Q(b0, k2 * 2 + 2) }
            MFMA_STEP_Q(b1, k2 * 2 + 1)
        }
    }
    __syncthreads();
    // per-wave D buffer in A's region: 32 rows x 96 cols fp32, stride 100
    float* Dl = (float*)A + w * 4224;
#pragma unroll
    for (int i = 0; i < 6; ++i) {
        const int col0 = i * 16 + (lane >> 4) * 4;
#pragma unroll
        for (int m = 0; m < 2; ++m) {
            const int rl = m * 16 + (lane & 15);
            *(float4*)&Dl[rl * 100 + col0] =
                make_float4(acc[i][m][0], acc[i][m][1], acc[i][m][2], acc[i][m][3]);
        }
    }
    __syncthreads();
#pragma unroll
    for (int it = 0; it < 4; ++it) {
        int idx = it * 64 + lane;     // 32 rows x 8 heads
        int rl = idx >> 3;
        int h = idx & 7;
        int row = m0 + w * 32 + rl;
        float rx = refpt[(size_t)row * 2 + 0] * 128.f - 0.5f;
        float ry = refpt[(size_t)row * 2 + 1] * 128.f - 0.5f;
        float l0 = Dl[rl * 100 + 64 + h * 4 + 0] + b_attn[h * 4 + 0];
        float l1 = Dl[rl * 100 + 64 + h * 4 + 1] + b_attn[h * 4 + 1];
        float l2 = Dl[rl * 100 + 64 + h * 4 + 2] + b_attn[h * 4 + 2];
        float l3 = Dl[rl * 100 + 64 + h * 4 + 3] + b_attn[h * 4 + 3];
        float mx = fmaxf(fmaxf(l0, l1), fmaxf(l2, l3));
        float e0 = __expf(l0 - mx), e1 = __expf(l1 - mx);
        float e2 = __expf(l2 - mx), e3 = __expf(l3 - mx);
        float inv = 1.f / (e0 + e1 + e2 + e3);
        float ww[4] = {e0 * inv, e1 * inv, e2 * inv, e3 * inv};
#pragma unroll
        for (int p = 0; p < 4; ++p) {
            float ox = Dl[rl * 100 + h * 8 + p * 2 + 0] + b_off[h * 8 + p * 2 + 0];
            float oy = Dl[rl * 100 + h * 8 + p * 2 + 1] + b_off[h * 8 + p * 2 + 1];
            samples[((size_t)row * 8 + h) * 4 + p] = make_float4(rx + ox, ry + oy, ww[p], 0.f);
        }
    }
}

// ---------------- bilinear gather + attention-weighted sum -> bf16 acc ----------------
__global__ __launch_bounds__(256) void k_gather(
    const unsigned short* __restrict__ value, const float4* __restrict__ samples,
    unsigned short* __restrict__ accb) {
    const int tid = blockIdx.x * 256 + threadIdx.x;
    const int sub = tid & 3;         // channel-quad (8 channels)
    const int t = tid >> 2;          // (b*NQ+q)*8 + h
    const int h = t & 7;
    const int bq = t >> 3;
    const int b = bq >> 14;
    const unsigned short* vb = value + ((size_t)b << 14) * 256 + h * 32 + sub * 8;
    float a0 = 0.f, a1 = 0.f, a2 = 0.f, a3 = 0.f;
    float a4 = 0.f, a5 = 0.f, a6 = 0.f, a7 = 0.f;
#pragma unroll
    for (int p = 0; p < 4; ++p) {
        float4 s = samples[(size_t)t * 4 + p];
        float xf = floorf(s.x), yf = floorf(s.y);
        float fx = s.x - xf, fy = s.y - yf;
        int x0 = (int)xf, y0 = (int)yf;
        int x1 = x0 + 1, y1 = y0 + 1;
        float wgt = s.z;
        bool bx0 = (unsigned)x0 < 128u, bx1 = (unsigned)x1 < 128u;
        bool by0 = (unsigned)y0 < 128u, by1 = (unsigned)y1 < 128u;
        float wt[4];
        wt[0] = (bx0 && by0) ? (1.f - fx) * (1.f - fy) * wgt : 0.f;
        wt[1] = (bx1 && by0) ? fx * (1.f - fy) * wgt : 0.f;
        wt[2] = (bx0 && by1) ? (1.f - fx) * fy * wgt : 0.f;
        wt[3] = (bx1 && by1) ? fx * fy * wgt : 0.f;
        int xc0 = min(max(x0, 0), 127), xc1 = min(max(x1, 0), 127);
        int yc0 = min(max(y0, 0), 127), yc1 = min(max(y1, 0), 127);
        int pix[4];
        pix[0] = yc0 * 128 + xc0; pix[1] = yc0 * 128 + xc1;
        pix[2] = yc1 * 128 + xc0; pix[3] = yc1 * 128 + xc1;
#pragma unroll
        for (int tp = 0; tp < 4; ++tp) {
            uint4 u = *(const uint4*)(vb + (size_t)pix[tp] * 256);
            float w = wt[tp];
            a0 = fmaf(w, blo(u.x), a0); a1 = fmaf(w, bhi(u.x), a1);
            a2 = fmaf(w, blo(u.y), a2); a3 = fmaf(w, bhi(u.y), a3);
            a4 = fmaf(w, blo(u.z), a4); a5 = fmaf(w, bhi(u.z), a5);
            a6 = fmaf(w, blo(u.w), a6); a7 = fmaf(w, bhi(u.w), a7);
        }
    }
    uint4 r;
    r.x = (unsigned)f2bf(a0) | ((unsigned)f2bf(a1) << 16);
    r.y = (unsigned)f2bf(a2) | ((unsigned)f2bf(a3) << 16);
    r.z = (unsigned)f2bf(a4) | ((unsigned)f2bf(a5) << 16);
    r.w = (unsigned)f2bf(a6) | ((unsigned)f2bf(a7) << 16);
    *(uint4*)(accb + (size_t)bq * 256 + h * 32 + sub * 8) = r;
}

// ---------------- out GEMM + bias + gated residual ----------------
__global__ __launch_bounds__(256) void k_out(
    const unsigned short* __restrict__ accb, const unsigned short* __restrict__ WtO,
    const float* __restrict__ b_out, const float* __restrict__ gamma,
    const float* __restrict__ query, float* __restrict__ out) {
    __shared__ unsigned short A[128 * 264];
    const int m0 = blockIdx.x * 128;
    STAGE_A(accb)
    __syncthreads();
    const int lane = threadIdx.x & 63;
    const int w = threadIdx.x >> 6;
    const int lrow = lane & 15, lk = (lane >> 4) * 8;
    f32x4 acc[4][8];
#pragma unroll
    for (int i = 0; i < 4; ++i)
#pragma unroll
        for (int m = 0; m < 8; ++m) acc[i][m] = (f32x4){0.f, 0.f, 0.f, 0.f};
#define LOADB_O(dst, kk)                                                              \
    _Pragma("unroll") for (int i = 0; i < 4; ++i) dst[i] =                            \
        *(const bf16x8*)(WtO + (size_t)((w * 4 + i) * 16 + lrow) * 256 + (kk) * 32 + lk);
    {
        bf16x8 b0[4], b1[4];
        LOADB_O(b0, 0)
#pragma unroll
        for (int k2 = 0; k2 < 4; ++k2) {
            LOADB_O(b1, k2 * 2 + 1)
            MFMA_STEP_V(b0, k2 * 2)
            if (k2 < 3) { LOADB_O(b0, k2 * 2 + 2) }
            MFMA_STEP_V(b1, k2 * 2 + 1)
        }
    }
    const int g = lane >> 4;
    float4 bo[4], gm[4];
#pragma unroll
    for (int i = 0; i < 4; ++i) {
        bo[i] = *(const float4*)(b_out + (w * 4 + i) * 16 + g * 4);
        gm[i] = *(const float4*)(gamma + (w * 4 + i) * 16 + g * 4);
    }
#pragma unroll
    for (int m = 0; m < 8; ++m) {
        const size_t row = (size_t)(m0 + m * 16 + (lane & 15));
#pragma unroll
        for (int i = 0; i < 4; ++i) {
            const int col0 = (w * 4 + i) * 16 + g * 4;
            float4 q = *(const float4*)(query + row * 256 + col0);
            float4 o;
            o.x = q.x + gm[i].x * (acc[i][m][0] + bo[i].x);
            o.y = q.y + gm[i].y * (acc[i][m][1] + bo[i].y);
            o.z = q.z + gm[i].z * (acc[i][m][2] + bo[i].z);
            o.w = q.w + gm[i].w * (acc[i][m][3] + bo[i].w);
            *(float4*)(out + row * 256 + col0) = o;
        }
    }
}

extern "C" void kernel_launch(void* const* d_in, const int* in_sizes, int n_in,
                              void* d_out, int out_size, void* d_ws, size_t ws_size,
                              hipStream_t stream) {
    const float* query    = (const float*)d_in[0];
    const float* feat     = (const float*)d_in[1];
    const float* refpt    = (const float*)d_in[2];
    const float* qn_scale = (const float*)d_in[5];
    const float* qn_bias  = (const float*)d_in[6];
    const float* fn_scale = (const float*)d_in[7];
    const float* fn_bias  = (const float*)d_in[8];
    const float* W_value  = (const float*)d_in[9];
    const float* b_value  = (const float*)d_in[10];
    const float* W_off    = (const float*)d_in[11];
    const float* b_off    = (const float*)d_in[12];
    const float* W_attn   = (const float*)d_in[13];
    const float* b_attn   = (const float*)d_in[14];
    const float* W_out    = (const float*)d_in[15];
    const float* b_out    = (const float*)d_in[16];
    const float* gamma    = (const float*)d_in[17];
    float* out = (float*)d_out;

    char* ws = (char*)d_ws;
    unsigned short* WtV   = (unsigned short*)(ws);
    unsigned short* WtO   = (unsigned short*)(ws + 131072);
    unsigned short* WtC   = (unsigned short*)(ws + 262144);
    unsigned short* value = (unsigned short*)(ws + 311296);
    // region A (33554432 B): lnf, later overwritten by samples (stream-ordered)
    char* regA = ws + 311296 + 33554432;
    // region B (33554432 B): lnq, later overwritten by accb (stream-ordered)
    char* regB = ws + 311296 + 2 * 33554432;
    unsigned short* lnf     = (unsigned short*)regA;
    float4*         samples = (float4*)regA;
    unsigned short* lnq     = (unsigned short*)regB;
    unsigned short* accb    = (unsigned short*)regB;

    hipLaunchKernelGGL(k_prep, dim3(608), dim3(256), 0, stream,
                       W_value, W_off, W_attn, W_out, WtV, WtC, WtO);
    hipLaunchKernelGGL(k_ln, dim3(4096), dim3(256), 0, stream,
                       feat, query, fn_scale, fn_bias, qn_scale, qn_bias, lnf, lnq);
    hipLaunchKernelGGL(k_value, dim3(512), dim3(256), 0, stream,
                       lnf, b_value, WtV, value);
    hipLaunchKernelGGL(k_qoff, dim3(512), dim3(256), 0, stream,
                       lnq, refpt, b_off, b_attn, WtC, samples);
    hipLaunchKernelGGL(k_gather, dim3(8192), dim3(256), 0, stream,
                       value, samples, accb);
    hipLaunchKernelGGL(k_out, dim3(512), dim3(256), 0, stream,
                       accb, WtO, b_out, gamma, query, out);
}